// Round 6
// baseline (345.660 us; speedup 1.0000x reference)
//
#include <hip/hip_runtime.h>
#include <math.h>

#define B_TOT 512
#define S_LEN 256
#define D_IN  64
#define HDIM  128
#define WAVES_PER_BLOCK 8   // 512 threads -> 2 waves per SIMD (co-residency)

// ---- fast scalar ops (raw HW instructions; ~1-2 ulp, threshold is 1.5e-2) ----
__device__ __forceinline__ float rcp_f(float x) { return __builtin_amdgcn_rcpf(x); }
__device__ __forceinline__ float rsq_f(float x) { return __builtin_amdgcn_rsqf(x); }
__device__ __forceinline__ float sig_f(float x) { return rcp_f(1.0f + __expf(-x)); }
__device__ __forceinline__ float tanh_f(float x) { return 1.0f - 2.0f * rcp_f(1.0f + __expf(2.0f * x)); }

// ---- DPP butterfly add (VALU pipe) ----
template<int CTRL>
__device__ __forceinline__ float dpp_add(float v) {
    int t = __builtin_amdgcn_update_dpp(0, __float_as_int(v), CTRL, 0xF, 0xF, true);
    return v + __int_as_float(t);
}

// 64-lane all-reduce: 4 DPP stages -> 16-lane row sums, then 4 readlanes + 3 adds.
// All per-wave ops: safe with multiple waves per block.
__device__ __forceinline__ float allsum64(float v) {
    v = dpp_add<0xB1>(v);    // xor 1
    v = dpp_add<0x4E>(v);    // xor 2
    v = dpp_add<0x141>(v);   // xor 4 (row_half_mirror)
    v = dpp_add<0x140>(v);   // xor 8 (row_mirror)
    int r0 = __builtin_amdgcn_readlane(__float_as_int(v), 0);
    int r1 = __builtin_amdgcn_readlane(__float_as_int(v), 16);
    int r2 = __builtin_amdgcn_readlane(__float_as_int(v), 32);
    int r3 = __builtin_amdgcn_readlane(__float_as_int(v), 48);
    return (__int_as_float(r0) + __int_as_float(r1))
         + (__int_as_float(r2) + __int_as_float(r3));
}

__global__ void __launch_bounds__(64 * WAVES_PER_BLOCK, 2) qlstm_kernel(
    const float* __restrict__ x,    // (B,S,D)
    const float* __restrict__ Win,  // (192,4)
    const float* __restrict__ bin,  // (4)
    const float* __restrict__ Wout, // (4,128)
    const float* __restrict__ bout, // (128)
    const float* __restrict__ wf,   // (1,3,4)
    const float* __restrict__ wi,
    const float* __restrict__ wu,
    const float* __restrict__ wo,
    float* __restrict__ out)        // outs (B,S,128) ++ hT (B,128) ++ cT (B,128)
{
    const int b = blockIdx.x * WAVES_PER_BLOCK + (threadIdx.x >> 6); // batch chain
    const int l = threadIdx.x & 63;  // lane; owns hidden units l and l+64

    // ---- per-lane constant weights ----
    const float4* W4 = reinterpret_cast<const float4*>(Win);
    const float4 wh0 = W4[l];        // W_in rows 0..63   (h part, unit l)
    const float4 wh1 = W4[64 + l];   // W_in rows 64..127 (h part, unit 64+l)
    const float4 wx  = W4[128 + l];  // W_in rows 128..191 (x part, feature l)
    // b_in folded in pre-reduction: each lane adds b/64, 64-lane sum gives b.
    const float4 bn4 = *reinterpret_cast<const float4*>(bin);
    const float bn0 = bn4.x * 0.015625f, bn1 = bn4.y * 0.015625f,
                bn2 = bn4.z * 0.015625f, bn3 = bn4.w * 0.015625f;

    float Wo0[4], Wo1[4];
#pragma unroll
    for (int q = 0; q < 4; ++q) {
        Wo0[q] = Wout[q * HDIM + l];
        Wo1[q] = Wout[q * HDIM + 64 + l];
    }
    const float bo0 = bout[l];
    const float bo1 = bout[64 + l];

    // ---- per-(gate,qubit) measurement coefficients u = (-sin b, cos b sin a, cos b cos a)
    float U[4][4][3];
    {
        const float* wg[4] = {wf, wi, wu, wo};
#pragma unroll
        for (int g = 0; g < 4; ++g) {
#pragma unroll
            for (int q = 0; q < 4; ++q) {
                float a  = wg[g][q];
                float be = wg[g][4 + q];
                float sa = sinf(a),  ca = cosf(a);
                float sb = sinf(be), cb = cosf(be);
                U[g][q][0] = -sb;
                U[g][q][1] = cb * sa;
                U[g][q][2] = cb * ca;
            }
        }
    }

    // ---- recurrent state ----
    float h0 = 0.f, h1 = 0.f, c0 = 0.f, c1 = 0.f;

    const float* xb = x + (size_t)b * (S_LEN * D_IN) + l;
    float* ob = out + (size_t)b * (S_LEN * HDIM) + l;

    // one full LSTM step; xval is this step's x feature for this lane
    auto step = [&](float xval) {
        float xc0 = fmaf(xval, wx.x, bn0);
        float xc1 = fmaf(xval, wx.y, bn1);
        float xc2 = fmaf(xval, wx.z, bn2);
        float xc3 = fmaf(xval, wx.w, bn3);
        float p0 = fmaf(h0, wh0.x, fmaf(h1, wh1.x, xc0));
        float p1 = fmaf(h0, wh0.y, fmaf(h1, wh1.y, xc1));
        float p2 = fmaf(h0, wh0.z, fmaf(h1, wh1.z, xc2));
        float p3 = fmaf(h0, wh0.w, fmaf(h1, wh1.w, xc3));
        float ys[4];
        ys[0] = allsum64(p0);
        ys[1] = allsum64(p1);
        ys[2] = allsum64(p2);
        ys[3] = allsum64(p3);

        // Bloch vectors (arctan's cancel analytically)
        float nx[4], ny[4], nz[4];
#pragma unroll
        for (int q = 0; q < 4; ++q) {
            float y   = ys[q];
            float y2s = y * y;
            float r1  = rsq_f(fmaf(y, y, 1.0f));
            float r2  = rsq_f(fmaf(y2s, y2s, 1.0f));
            float xx  = r1 * r2;
            nx[q] = xx;
            ny[q] = y2s * xx;
            nz[q] = -y * r1;
        }

        // Pauli-string products (CNOT-ring conjugation)
        float nz01 = nz[0] * nz[1];
        float nz23 = nz[2] * nz[3];
        float TX[4], TY[4], TZ[4];
        TX[0] = nx[0] * nx[1];
        TX[1] = nx[1] * nx[2];
        TX[2] = nx[2] * nx[3];
        TX[3] = TX[0] * nx[3];
        TZ[0] = nz[1] * nz23;
        TZ[1] = nz01;
        TZ[2] = nz01 * nz[2];
        TZ[3] = nz01 * nz23;
        TY[0] = (nx[0] * ny[1]) * nz23;
        TY[1] = (nz[0] * ny[1]) * nx[2];
        TY[2] = (nz01 * ny[2]) * nx[3];
        TY[3] = -(ny[0] * ny[1]) * (nz[2] * ny[3]);

        float pre0[4], pre1[4];
#pragma unroll
        for (int g = 0; g < 4; ++g) {
            float s0 = bo0, s1 = bo1;
#pragma unroll
            for (int q = 0; q < 4; ++q) {
                float z = fmaf(U[g][q][0], TX[q],
                          fmaf(U[g][q][1], TY[q],
                               U[g][q][2] * TZ[q]));
                s0 = fmaf(z, Wo0[q], s0);
                s1 = fmaf(z, Wo1[q], s1);
            }
            pre0[g] = s0; pre1[g] = s1;
        }

        float f0 = sig_f(pre0[0]),  f1 = sig_f(pre1[0]);
        float i0 = sig_f(pre0[1]),  i1 = sig_f(pre1[1]);
        float g0 = tanh_f(pre0[2]), g1 = tanh_f(pre1[2]);
        float o0 = sig_f(pre0[3]),  o1 = sig_f(pre1[3]);
        c0 = fmaf(f0, c0, i0 * g0);
        c1 = fmaf(f1, c1, i1 * g1);
        h0 = o0 * tanh_f(c0);
        h1 = o1 * tanh_f(c1);
    };

    // ---- software-pipelined groups of 4 steps ----
    float xg[4], xn[4];
#pragma unroll
    for (int j = 0; j < 4; ++j) {
        xg[j] = xb[(size_t)j * D_IN];
        xn[j] = xb[(size_t)(4 + j) * D_IN];
    }

    float ph0[4], ph1[4];

    // group 0: compute only
#pragma unroll
    for (int j = 0; j < 4; ++j) {
        step(xg[j]);
        ph0[j] = h0; ph1[j] = h1;
    }

    for (int g = 1; g < S_LEN / 4; ++g) {
        const int tprev = (g - 1) * 4;
        float* op = ob + (size_t)tprev * HDIM;
#pragma unroll
        for (int j = 0; j < 4; ++j) {
            op[(size_t)j * HDIM]      = ph0[j];
            op[(size_t)j * HDIM + 64] = ph1[j];
        }
#pragma unroll
        for (int j = 0; j < 4; ++j) xg[j] = xn[j];
#pragma unroll
        for (int j = 0; j < 4; ++j) {
            int tn = (g + 1) * 4 + j;
            if (tn > S_LEN - 1) tn = S_LEN - 1;
            xn[j] = xb[(size_t)tn * D_IN];
        }
        float nh0[4], nh1[4];
#pragma unroll
        for (int j = 0; j < 4; ++j) {
            step(xg[j]);
            nh0[j] = h0; nh1[j] = h1;
        }
#pragma unroll
        for (int j = 0; j < 4; ++j) { ph0[j] = nh0[j]; ph1[j] = nh1[j]; }
    }

    // epilogue: store last group
    {
        const int tprev = S_LEN - 4;
        float* op = ob + (size_t)tprev * HDIM;
#pragma unroll
        for (int j = 0; j < 4; ++j) {
            op[(size_t)j * HDIM]      = ph0[j];
            op[(size_t)j * HDIM + 64] = ph1[j];
        }
    }

    // final h, c
    float* hT = out + (size_t)B_TOT * S_LEN * HDIM;
    float* cT = hT + (size_t)B_TOT * HDIM;
    hT[(size_t)b * HDIM + l]      = h0;
    hT[(size_t)b * HDIM + 64 + l] = h1;
    cT[(size_t)b * HDIM + l]      = c0;
    cT[(size_t)b * HDIM + 64 + l] = c1;
}

extern "C" void kernel_launch(void* const* d_in, const int* in_sizes, int n_in,
                              void* d_out, int out_size, void* d_ws, size_t ws_size,
                              hipStream_t stream) {
    qlstm_kernel<<<dim3(B_TOT / WAVES_PER_BLOCK), dim3(64 * WAVES_PER_BLOCK), 0, stream>>>(
        (const float*)d_in[0],  // x
        (const float*)d_in[1],  // W_in
        (const float*)d_in[2],  // b_in
        (const float*)d_in[3],  // W_out
        (const float*)d_in[4],  // b_out
        (const float*)d_in[5],  // w_f
        (const float*)d_in[6],  // w_i
        (const float*)d_in[7],  // w_u
        (const float*)d_in[8],  // w_o
        (float*)d_out);
}